// Round 1
// baseline (88.612 us; speedup 1.0000x reference)
//
#include <hip/hip_runtime.h>

#define BB 4
#define STN 9
#define CC 3
#define HH 288
#define WW 288
#define KF 5
#define OHH 96
#define OWW 96
#define NPIX (OHH*OWW)        // 9216
#define KK 25                 // KF*KF
#define TILE 16               // pixels per block
#define NOI (STN*STN)         // 81
#define WTILE (TILE*KK)       // 400
#define LDSW (NOI*WTILE)      // 32400 floats = 129.6 KB

__global__ __launch_bounds__(256)
void lfk_kernel(const float* __restrict__ lf,
                const float* __restrict__ wts,
                const float* __restrict__ bias,
                float* __restrict__ out)
{
    __shared__ float w_lds[LDSW];
    const int tid = threadIdx.x;
    const int p0  = blockIdx.x * TILE;    // base pixel of this tile

    // ---- Phase 1: stage weights for this pixel tile, all (o,i), coalesced ----
    // global layout: ((o*9+i)*NPIX + pix)*KK + k ; for a tile the chunk per (o,i)
    // is WTILE contiguous floats starting at oi*NPIX*KK + p0*KK.
    for (int idx = tid; idx < LDSW; idx += 256) {
        int oi  = idx / WTILE;
        int rem = idx - oi * WTILE;
        w_lds[idx] = wts[oi * (NPIX * KK) + p0 * KK + rem];
    }
    __syncthreads();

    // ---- Phase 2: 192 workers = (pix 16) x (b*c 12), each does all 9 o ----
    if (tid >= TILE * (BB * CC)) return;
    const int pix = tid & (TILE - 1);
    const int bc  = tid >> 4;             // 0..11
    const int b   = bc / CC;
    const int c   = bc - b * CC;

    const int g  = p0 + pix;              // global pixel
    const int oh = g / OWW;
    const int ow = g - oh * OWW;
    const int y0 = oh * 3 - 2;            // top/left pad = 2, no bottom/right pad
    const int x0 = ow * 3 - 2;

    float acc[STN];
    #pragma unroll
    for (int o = 0; o < STN; ++o) acc[o] = 0.f;

    for (int i = 0; i < STN; ++i) {
        const float* lfb = lf + ((b * STN + i) * CC + c) * (HH * WW);
        float p[KK];
        #pragma unroll
        for (int kh = 0; kh < KF; ++kh) {
            const int y = y0 + kh;
            #pragma unroll
            for (int kw = 0; kw < KF; ++kw) {
                const int x = x0 + kw;
                p[kh * KF + kw] = (y >= 0 && x >= 0) ? lfb[y * WW + x] : 0.f;
            }
        }
        #pragma unroll
        for (int o = 0; o < STN; ++o) {
            const float* wrow = &w_lds[(o * STN + i) * WTILE + pix * KK];
            #pragma unroll
            for (int k = 0; k < KK; ++k)
                acc[o] += wrow[k] * p[k];
        }
    }

    #pragma unroll
    for (int o = 0; o < STN; ++o) {
        float v = acc[o] + bias[o * NPIX + g];
        v = fminf(fmaxf(v, 0.f), 1.f);
        out[((b * STN + o) * CC + c) * NPIX + g] = v;
    }
}

extern "C" void kernel_launch(void* const* d_in, const int* in_sizes, int n_in,
                              void* d_out, int out_size, void* d_ws, size_t ws_size,
                              hipStream_t stream) {
    const float* lf   = (const float*)d_in[0];
    const float* wts  = (const float*)d_in[1];
    const float* bias = (const float*)d_in[2];
    float* out = (float*)d_out;
    (void)d_ws; (void)ws_size; (void)in_sizes; (void)n_in; (void)out_size;

    dim3 grid(NPIX / TILE);   // 576 blocks
    dim3 block(256);
    lfk_kernel<<<grid, block, 0, stream>>>(lf, wts, bias, out);
}

// Round 2
// 56.946 us; speedup vs baseline: 1.5561x; 1.5561x over previous
//
#include <hip/hip_runtime.h>

#define STN 9
#define CC 3
#define NB 4
#define HH 288
#define WW 288
#define KF 5
#define KK 25
#define OWN 96
#define NPIX 9216
#define TILE 16
#define OG 3                    // o's per block
#define PST 28                  // padded per-pixel weight stride in LDS (16B-aligned rows)
#define LBUF (OG*TILE*PST)      // 1344 floats
#define PLANE (HH*WW)           // 82944
#define WCHUNK4 (NPIX*KK/4)     // 57600 float4 per (o,i)

__global__ __launch_bounds__(64, 2)
void lfk2(const float* __restrict__ lf, const float* __restrict__ wts,
          const float* __restrict__ bias, float* __restrict__ out)
{
    __shared__ float wl[2][LBUF];
    const int lane = threadIdx.x;            // 64 = 1 wave
    const int tile = blockIdx.x / OG;
    const int og   = blockIdx.x - tile * OG;
    const int p0   = tile * TILE;
    const int pix  = lane & (TILE - 1);
    const int b    = lane >> 4;              // 0..3

    const int g  = p0 + pix;
    const int oh = g / OWN;
    const int ow = g - oh * OWN;
    const int y0 = oh * 3 - 2;               // pt = pl = 2, no bottom/right pad
    const int x0 = ow * 3 - 2;

    const float4* __restrict__ w4 = (const float4*)wts;

    // staging registers: 300 float4 per i-step over 64 lanes -> up to 5 each
    float4 r0, r1, r2, r3, r4;

    auto stage_load = [&](int i) {
        // idx = lane + 64*j ; chunk per o_local: 100 f4, global-contiguous
        #pragma unroll
        for (int j = 0; j < 5; ++j) {
            const int idx = lane + j * 64;
            if (j < 4 || idx < 300) {
                const int ol  = idx / 100;
                const int rem = idx - ol * 100;
                const float4 v = w4[((og * OG + ol) * STN + i) * WCHUNK4 + tile * 100 + rem];
                if (j == 0) r0 = v; else if (j == 1) r1 = v; else if (j == 2) r2 = v;
                else if (j == 3) r3 = v; else r4 = v;
            }
        }
    };
    auto stage_write = [&](int i) {
        float* dst = wl[i & 1];
        #pragma unroll
        for (int j = 0; j < 5; ++j) {
            const int idx = lane + j * 64;
            if (j < 4 || idx < 300) {
                const int ol  = idx / 100;
                const int rem = idx - ol * 100;
                const int f0  = rem * 4;
                float4 v;
                if (j == 0) v = r0; else if (j == 1) v = r1; else if (j == 2) v = r2;
                else if (j == 3) v = r3; else v = r4;
                float vv[4] = {v.x, v.y, v.z, v.w};
                #pragma unroll
                for (int q = 0; q < 4; ++q) {
                    const int f  = f0 + q;
                    const int pd = f / 25;
                    const int k  = f - pd * 25;
                    dst[(ol * TILE + pd) * PST + k] = vv[q];
                }
            }
        }
    };

    float acc[OG][CC];
    #pragma unroll
    for (int oc = 0; oc < OG; ++oc)
        #pragma unroll
        for (int c = 0; c < CC; ++c) acc[oc][c] = 0.f;

    stage_load(0);

    for (int i = 0; i < STN; ++i) {
        stage_write(i);
        if (i < STN - 1) stage_load(i + 1);

        // ---- patches for (b, i, c=0..2), 25 window values each ----
        float p[CC][KK];
        if (y0 >= 0 && x0 >= 0) {
            #pragma unroll
            for (int c = 0; c < CC; ++c) {
                const float* lfb = lf + ((b * STN + i) * CC + c) * PLANE + y0 * WW + x0;
                #pragma unroll
                for (int kh = 0; kh < KF; ++kh)
                    #pragma unroll
                    for (int kw = 0; kw < KF; ++kw)
                        p[c][kh * KF + kw] = lfb[kh * WW + kw];
            }
        } else {
            #pragma unroll
            for (int c = 0; c < CC; ++c) {
                const float* lfb = lf + ((b * STN + i) * CC + c) * PLANE;
                #pragma unroll
                for (int kh = 0; kh < KF; ++kh) {
                    const int y = y0 + kh;
                    #pragma unroll
                    for (int kw = 0; kw < KF; ++kw) {
                        const int x = x0 + kw;
                        p[c][kh * KF + kw] = (y >= 0 && x >= 0) ? lfb[y * WW + x] : 0.f;
                    }
                }
            }
        }

        // ---- contraction: weights from LDS (aligned 112B rows -> b128 reads) ----
        const float* wb = wl[i & 1];
        #pragma unroll
        for (int oc = 0; oc < OG; ++oc) {
            const float* wrow = wb + (oc * TILE + pix) * PST;
            float w[KK];
            #pragma unroll
            for (int k = 0; k < KK; ++k) w[k] = wrow[k];
            #pragma unroll
            for (int c = 0; c < CC; ++c)
                #pragma unroll
                for (int k = 0; k < KK; ++k)
                    acc[oc][c] = fmaf(w[k], p[c][k], acc[oc][c]);
        }
    }

    // ---- epilogue: bias + clip + store ----
    #pragma unroll
    for (int oc = 0; oc < OG; ++oc) {
        const int o  = og * OG + oc;
        const float bo = bias[o * NPIX + g];
        #pragma unroll
        for (int c = 0; c < CC; ++c) {
            float v = acc[oc][c] + bo;
            v = fminf(fmaxf(v, 0.f), 1.f);
            out[((b * STN + o) * CC + c) * NPIX + g] = v;
        }
    }
}

extern "C" void kernel_launch(void* const* d_in, const int* in_sizes, int n_in,
                              void* d_out, int out_size, void* d_ws, size_t ws_size,
                              hipStream_t stream) {
    const float* lf   = (const float*)d_in[0];
    const float* wts  = (const float*)d_in[1];
    const float* bias = (const float*)d_in[2];
    float* out = (float*)d_out;
    (void)d_ws; (void)ws_size; (void)in_sizes; (void)n_in; (void)out_size;

    dim3 grid((NPIX / TILE) * OG);   // 1728 single-wave blocks
    dim3 block(64);
    lfk2<<<grid, block, 0, stream>>>(lf, wts, bias, out);
}